// Round 9
// baseline (110.340 us; speedup 1.0000x reference)
//
#include <hip/hip_runtime.h>
#include <hip/hip_bf16.h>

#define N_IN   5023
#define B_SZ   64
#define H_DIM  256
#define NPAD   5120
#define NBD    192          // B_SZ * 3
#define SPLITZ 40           // gemm3 split-K slices, 128-wide (2 x 64 sub-chunks)
#define OUT_ELEMS (B_SZ * N_IN * 3)   // 964416

typedef short bf16x8 __attribute__((ext_vector_type(8)));
typedef float f32x4  __attribute__((ext_vector_type(4)));

__device__ inline void async_copy16(const void* g, void* l) {
    __builtin_amdgcn_global_load_lds(
        (const __attribute__((address_space(1))) unsigned int*)g,
        (__attribute__((address_space(3))) unsigned int*)l,
        16, 0, 0);
}

__device__ inline unsigned char to_fp8(float v) {
    int p = __builtin_amdgcn_cvt_pk_fp8_f32(v, 0.0f, 0, false);
    return (unsigned char)(p & 0xFF);
}

// ---- conv_all: z=0: key_w[i][h] -> k8 fp8 [5120][256] + keyT bf16 [256][5120]
//                z=1: query_w[h][o] -> q8 fp8 [5120][256] + qtb bf16 [5120][256] (*1/16)
//      q8/k8 hold UNSCALED values (sigma 0.0625, e4m3 normal range).
//      Also zeroes l1 (z=0 blocks). ----
__global__ void conv_all(const float* __restrict__ kw, const float* __restrict__ qw,
                         unsigned char* __restrict__ k8, short* __restrict__ keyT,
                         unsigned char* __restrict__ q8, short* __restrict__ qtb,
                         float* __restrict__ l1) {
    __shared__ float tile[32][33];
    const int hb = blockIdx.x * 32;      // 8 tiles over H
    const int nb = blockIdx.y * 32;      // 160 tiles over NPAD
    const int tx = threadIdx.x;          // 32
    const int ty = threadIdx.y;          // 8
    if (blockIdx.z == 0) {
        for (int j = 0; j < 32; j += 8) {
            int i = nb + ty + j;
            int h = hb + tx;
            float v = (i < N_IN) ? kw[(size_t)i * H_DIM + h] : 0.0f;
            tile[ty + j][tx] = v;
            k8[(size_t)i * H_DIM + h] = to_fp8(v);
        }
        __syncthreads();
        __hip_bfloat16* kt = (__hip_bfloat16*)keyT;
        for (int j = 0; j < 32; j += 8) {
            int h = hb + ty + j;
            int i = nb + tx;
            kt[(size_t)h * NPAD + i] = __float2bfloat16(tile[tx][ty + j]);
        }
        if (blockIdx.x == 0 && ty == 0) l1[nb + tx] = 0.0f;
    } else {
        for (int j = 0; j < 32; j += 8) {
            int h = hb + ty + j;
            int o = nb + tx;
            tile[ty + j][tx] = (o < N_IN) ? qw[(size_t)h * N_IN + o] : 0.0f;
        }
        __syncthreads();
        __hip_bfloat16* qt = (__hip_bfloat16*)qtb;
        for (int j = 0; j < 32; j += 8) {
            int o = nb + ty + j;
            int h = hb + tx;
            float v = tile[tx][ty + j];
            qt[(size_t)o * H_DIM + h] = __float2bfloat16(v * 0.0625f);
            q8[(size_t)o * H_DIM + h] = to_fp8(v);
        }
    }
}

// ---- GEMM_L1 (fp8): l1[i] = sum_o |sum_h q8[o][h]*k8[i][h]| (unscaled by 16^2;
//      folded out downstream). M=N=5120, K=256, tile 128x128, BK=128 (2 rounds),
//      LDS 2x16KB, XOR-swizzled 16B slots (key = row&7). ----
__launch_bounds__(256)
__global__ void gemm_l1(const unsigned char* __restrict__ q8,
                        const unsigned char* __restrict__ k8,
                        float* __restrict__ l1) {
    __shared__ unsigned char As8[128 * 128];   // 16 KB
    __shared__ unsigned char Bs8[128 * 128];   // 16 KB
    const int bm = blockIdx.x, bn = blockIdx.y;
    const int tid = threadIdx.x, lane = tid & 63, wid = tid >> 6;
    const int wave_m = wid >> 1, wave_n = wid & 1;
    const int r = lane >> 3;          // 0..7 row within chunk
    const int s = lane & 7;           // 0..7 16B slot
    const int quad = lane >> 4, cit = lane & 15;
    const int xk = cit & 7;           // fragment xor key (= row & 7)

    f32x4 acc[4][4];
    const f32x4 zf = {0.f, 0.f, 0.f, 0.f};
    for (int a = 0; a < 4; ++a)
        for (int b = 0; b < 4; ++b) acc[a][b] = zf;

    for (int kb = 0; kb < H_DIM; kb += 128) {
        __syncthreads();
        const int koff = kb + ((s ^ r) << 4);   // swizzled global k-group
        for (int c = 0; c < 4; ++c) {
            int q = wid * 4 + c;                // 1KB chunk 0..15 (8 rows each)
            int row = q * 8 + r;
            async_copy16(q8 + (size_t)(bm * 128 + row) * H_DIM + koff, As8 + q * 1024);
            async_copy16(k8 + (size_t)(bn * 128 + row) * H_DIM + koff, Bs8 + q * 1024);
        }
        __syncthreads();
        for (int ki = 0; ki < 4; ++ki) {        // 4 x K=32 per round
            int g = ki * 2 + (quad >> 1);       // global 16B group within row
            int lo8 = (quad & 1) << 3;
            int slot = ((g ^ xk) << 4) + lo8;
            long af[4], bf[4];
            for (int t = 0; t < 4; ++t) {
                int am = wave_m * 64 + t * 16 + cit;
                af[t] = *(const long*)(As8 + am * 128 + slot);
                int bn_ = wave_n * 64 + t * 16 + cit;
                bf[t] = *(const long*)(Bs8 + bn_ * 128 + slot);
            }
            for (int tm = 0; tm < 4; ++tm)
                for (int tn = 0; tn < 4; ++tn)
                    acc[tm][tn] = __builtin_amdgcn_mfma_f32_16x16x32_fp8_fp8(
                        af[tm], bf[tn], acc[tm][tn], 0, 0, 0);
        }
    }

    for (int tn = 0; tn < 4; ++tn) {
        int ig = bn * 128 + wave_n * 64 + tn * 16 + cit;   // column i
        float p = 0.0f;
        for (int tm = 0; tm < 4; ++tm) {
            f32x4 c = acc[tm][tn];
            p += fabsf(c.x) + fabsf(c.y) + fabsf(c.z) + fabsf(c.w);
        }
        p += __shfl_xor(p, 16);
        p += __shfl_xor(p, 32);
        if (quad == 0) atomicAdd(&l1[ig], p);
    }
}

// ---- GEMM3_F (build_vmat fused): part2[z][bd][h] =
//      sum_{i in 128-chunk} vmat[bd][i] * keyT[h][i], two 64-wide sub-chunks
//      accumulated in registers. vmat built directly into padded LDS.
//      Grid (4 h-tiles, 40 z). Waves 2x2: wave tile 96x32. ----
#define AP 72    // As pitch in bf16: 144 B = 9*16 (aligned), 36 dw = +4 banks/row
__launch_bounds__(256)
__global__ void gemm3_f(const float* __restrict__ x, const float* __restrict__ vw,
                        const float* __restrict__ l1, const short* __restrict__ keyT,
                        float* __restrict__ part2) {
    __shared__ short As[NBD * AP];    // 27,648 B
    __shared__ short Bs[64 * 64];     // 8,192 B (XOR-swizzled 16B slots)
    const int bh = blockIdx.x;        // h tile (4)
    const int z  = blockIdx.y;        // 128-wide i chunk (40)
    const int tid = threadIdx.x, lane = tid & 63, wid = tid >> 6;
    const int wave_m = wid >> 1, wave_n = wid & 1;
    const int rr = lane >> 3, ss = lane & 7;
    const int quad = lane >> 4, cit = lane & 15;

    f32x4 acc[6][2];
    const f32x4 zf = {0.f, 0.f, 0.f, 0.f};
    for (int a = 0; a < 6; ++a)
        for (int b = 0; b < 2; ++b) acc[a][b] = zf;

    for (int sub = 0; sub < 2; ++sub) {
        const int ibase = z * 128 + sub * 64;
        __syncthreads();                       // LDS reuse across sub-chunks
        // ---- build vmat tile into As ----
        {
            const int i_loc = tid & 63;
            const int grp   = tid >> 6;            // 4 groups x 16 b
            const int i = ibase + i_loc;
            const bool ok = (i < N_IN);
            float rcp = 0.0f;
            if (ok) rcp = 1.0f / fmaxf(l1[i] * 0.0625f, 1e-12f);
            float w00 = vw[0], w01 = vw[1], w02 = vw[2];
            float w10 = vw[3], w11 = vw[4], w12 = vw[5];
            float w20 = vw[6], w21 = vw[7], w22 = vw[8];
            __hip_bfloat16* as = (__hip_bfloat16*)As;
            for (int bo = 0; bo < 16; ++bo) {
                int b = grp * 16 + bo;
                float x0 = 0.f, x1 = 0.f, x2 = 0.f;
                if (ok) {
                    const float* xp = x + ((size_t)b * N_IN + i) * 3;
                    x0 = xp[0]; x1 = xp[1]; x2 = xp[2];
                }
                as[(b * 3 + 0) * AP + i_loc] = __float2bfloat16((x0 * w00 + x1 * w01 + x2 * w02) * rcp);
                as[(b * 3 + 1) * AP + i_loc] = __float2bfloat16((x0 * w10 + x1 * w11 + x2 * w12) * rcp);
                as[(b * 3 + 2) * AP + i_loc] = __float2bfloat16((x0 * w20 + x1 * w21 + x2 * w22) * rcp);
            }
        }
        // ---- stage Bs (keyT rows, swizzled) ----
        for (int c = 0; c < 2; ++c) {
            int q = wid * 2 + c;                   // 0..7 (1KB chunks)
            int row = q * 8 + rr;                  // h local 0..63
            int koff = ibase + ((ss ^ (rr & 7)) << 3);
            async_copy16(keyT + (size_t)(bh * 64 + row) * NPAD + koff, Bs + q * 512);
        }
        __syncthreads();

        for (int kk = 0; kk < 64; kk += 32) {
            bf16x8 af[6], bf[2];
            int g = (kk >> 3) + quad;
            for (int t = 0; t < 6; ++t) {
                int row = wave_m * 96 + t * 16 + cit;
                af[t] = *(const bf16x8*)(As + row * AP + kk + quad * 8);
            }
            for (int t = 0; t < 2; ++t) {
                int row = wave_n * 32 + t * 16 + cit;
                bf[t] = *(const bf16x8*)(Bs + row * 64 + ((g ^ (cit & 7)) << 3));
            }
            for (int tm = 0; tm < 6; ++tm)
                for (int tn = 0; tn < 2; ++tn)
                    acc[tm][tn] = __builtin_amdgcn_mfma_f32_16x16x32_bf16(
                        af[tm], bf[tn], acc[tm][tn], 0, 0, 0);
        }
    }

    float* pz = part2 + (size_t)z * (NBD * H_DIM);
    for (int tn = 0; tn < 2; ++tn) {
        int h = bh * 64 + wave_n * 32 + tn * 16 + cit;
        for (int tm = 0; tm < 6; ++tm) {
            int bd0 = wave_m * 96 + tm * 16 + quad * 4;
            f32x4 c = acc[tm][tn];
            for (int r2 = 0; r2 < 4; ++r2)
                pz[(size_t)(bd0 + r2) * H_DIM + h] = c[r2];
        }
    }
}

// ---- reduce_T: T[bd][h] = bf16(sum_z part2[z][bd][h]) ----
__global__ void reduce_T(const float* __restrict__ part2, short* __restrict__ T) {
    int idx = blockIdx.x * 256 + threadIdx.x;     // < 49152
    float s = 0.0f;
    for (int z = 0; z < SPLITZ; ++z)
        s += part2[(size_t)z * (NBD * H_DIM) + idx];
    ((__hip_bfloat16*)T)[idx] = __float2bfloat16(s);
}

// ---- GEMM4: y[o][bd] = sum_h qt[o][h] * T[bd][h]; out via LDS transpose.
//      M-tile 32 -> 160 blocks. Waves 2x2: wave tile 16x96. XOR-swizzled LDS. ----
#define CS_PITCH 196
__launch_bounds__(256)
__global__ void gemm4(const short* __restrict__ qt, const short* __restrict__ T,
                      float* __restrict__ out) {
    __shared__ __align__(16) char smem[28672];   // staging 28KB / CS 25KB union
    short* As = (short*)smem;                    // 32 x 64 (4 KB, swizzled)
    short* Bs = (short*)(smem + 4096);           // 192 x 64 (24 KB, swizzled)
    const int bm = blockIdx.x;                   // 160
    const int tid = threadIdx.x, lane = tid & 63, wid = tid >> 6;
    const int wave_m = wid >> 1, wave_n = wid & 1;
    const int rr = lane >> 3, ss = lane & 7;
    const int quad = lane >> 4, cit = lane & 15;

    f32x4 acc[6];
    const f32x4 zf = {0.f, 0.f, 0.f, 0.f};
    for (int b = 0; b < 6; ++b) acc[b] = zf;

    for (int kb = 0; kb < H_DIM; kb += 64) {
        __syncthreads();
        const int koff = kb + ((ss ^ (rr & 7)) << 3);
        {   // As: 4 chunks, one per wave
            int row = wid * 8 + rr;              // 0..31
            async_copy16(qt + (size_t)(bm * 32 + row) * H_DIM + koff, As + wid * 512);
        }
        for (int c = 0; c < 6; ++c) {            // Bs: 24 chunks
            int q = wid * 6 + c;
            int row = q * 8 + rr;                // 0..191
            async_copy16(T + (size_t)row * H_DIM + koff, Bs + q * 512);
        }
        __syncthreads();
        for (int kk = 0; kk < 64; kk += 32) {
            bf16x8 af, bf[6];
            int g = (kk >> 3) + quad;
            int slot = (g ^ (cit & 7)) << 3;
            {
                int row = wave_m * 16 + cit;
                af = *(const bf16x8*)(As + row * 64 + slot);
            }
            for (int t = 0; t < 6; ++t) {
                int row = wave_n * 96 + t * 16 + cit;
                bf[t] = *(const bf16x8*)(Bs + row * 64 + slot);
            }
            for (int tn = 0; tn < 6; ++tn)
                acc[tn] = __builtin_amdgcn_mfma_f32_16x16x32_bf16(
                    af, bf[tn], acc[tn], 0, 0, 0);
        }
    }

    __syncthreads();
    float* cs = (float*)smem;             // [32][CS_PITCH]
    for (int tn = 0; tn < 6; ++tn) {
        int bd = wave_n * 96 + tn * 16 + cit;
        int o0 = wave_m * 16 + quad * 4;
        f32x4 c = acc[tn];
        for (int r2 = 0; r2 < 4; ++r2)
            cs[(o0 + r2) * CS_PITCH + bd] = c[r2];
    }
    __syncthreads();
    // out[b][o][d]: 64 b x (32 o x 3 d) = 6144 floats; 96-float runs per b.
    for (int it = 0; it < 24; ++it) {
        int flat = it * 256 + tid;        // 0..6143
        int b = flat / 96;
        int w = flat - b * 96;
        int o_l = w / 3, d = w - o_l * 3;
        int og = bm * 32 + o_l;
        if (og < N_IN)
            out[(size_t)b * (N_IN * 3) + (size_t)og * 3 + d] =
                cs[o_l * CS_PITCH + b * 3 + d];
    }
}

extern "C" void kernel_launch(void* const* d_in, const int* in_sizes, int n_in,
                              void* d_out, int out_size, void* d_ws, size_t ws_size,
                              hipStream_t stream) {
    const float* x  = (const float*)d_in[0];
    const float* kw = (const float*)d_in[1];
    const float* qw = (const float*)d_in[2];
    const float* vw = (const float*)d_in[3];
    float* out = (float*)d_out;

    char* w = (char*)d_ws;
    short* qtb  = (short*)(w + 0);                        // 5120*256*2 = 2,621,440
    short* keyT = (short*)(w + 2621440);                  // 256*5120*2 = 2,621,440
    unsigned char* q8 = (unsigned char*)(w + 5242880);    // 5120*256   = 1,310,720
    unsigned char* k8 = (unsigned char*)(w + 6553600);    // 5120*256   = 1,310,720
    float* l1    = (float*)(w + 7864320);                 // 5120*4     = 20,480
    float* part2 = (float*)(w + 7884800);                 // 40*192*256*4 = 7,864,320
    short* T     = (short*)(w + 15749120);                // 192*256*2  = 98,304
    // total: 15,847,424 bytes

    conv_all<<<dim3(H_DIM / 32, NPAD / 32, 2), dim3(32, 8), 0, stream>>>(
        kw, qw, k8, keyT, q8, qtb, l1);
    gemm_l1<<<dim3(NPAD / 128, NPAD / 128), 256, 0, stream>>>(q8, k8, l1);
    gemm3_f<<<dim3(H_DIM / 64, SPLITZ), 256, 0, stream>>>(x, vw, l1, keyT, part2);
    reduce_T<<<(NBD * H_DIM) / 256, 256, 0, stream>>>(part2, T);
    gemm4<<<NPAD / 32, 256, 0, stream>>>(qtb, T, out);
}

// Round 10
// 108.212 us; speedup vs baseline: 1.0197x; 1.0197x over previous
//
#include <hip/hip_runtime.h>
#include <hip/hip_bf16.h>

#define N_IN   5023
#define B_SZ   64
#define H_DIM  256
#define NPAD   5120
#define NBD    192          // B_SZ * 3
#define SPLITZ 80           // gemm3 split-K slices, 64-wide chunks
#define OUT_ELEMS (B_SZ * N_IN * 3)   // 964416

typedef short bf16x8 __attribute__((ext_vector_type(8)));
typedef float f32x4  __attribute__((ext_vector_type(4)));

__device__ inline void async_copy16(const void* g, void* l) {
    __builtin_amdgcn_global_load_lds(
        (const __attribute__((address_space(1))) unsigned int*)g,
        (__attribute__((address_space(3))) unsigned int*)l,
        16, 0, 0);
}

__device__ inline unsigned char to_fp8(float v) {
    int p = __builtin_amdgcn_cvt_pk_fp8_f32(v, 0.0f, 0, false);
    return (unsigned char)(p & 0xFF);
}

// ---- conv_all: z=0: key_w[i][h] -> k8 fp8 [5120][256] + keyT bf16 [256][5120]
//                z=1: query_w[h][o] -> q8 fp8 [5120][256] + qtb bf16 [5120][256] (*1/16)
//      q8/k8 hold UNSCALED values (sigma 0.0625, e4m3 normal range).
//      Also zeroes l1 (z=0 blocks). ----
__global__ void conv_all(const float* __restrict__ kw, const float* __restrict__ qw,
                         unsigned char* __restrict__ k8, short* __restrict__ keyT,
                         unsigned char* __restrict__ q8, short* __restrict__ qtb,
                         float* __restrict__ l1) {
    __shared__ float tile[32][33];
    const int hb = blockIdx.x * 32;      // 8 tiles over H
    const int nb = blockIdx.y * 32;      // 160 tiles over NPAD
    const int tx = threadIdx.x;          // 32
    const int ty = threadIdx.y;          // 8
    if (blockIdx.z == 0) {
        for (int j = 0; j < 32; j += 8) {
            int i = nb + ty + j;
            int h = hb + tx;
            float v = (i < N_IN) ? kw[(size_t)i * H_DIM + h] : 0.0f;
            tile[ty + j][tx] = v;
            k8[(size_t)i * H_DIM + h] = to_fp8(v);
        }
        __syncthreads();
        __hip_bfloat16* kt = (__hip_bfloat16*)keyT;
        for (int j = 0; j < 32; j += 8) {
            int h = hb + ty + j;
            int i = nb + tx;
            kt[(size_t)h * NPAD + i] = __float2bfloat16(tile[tx][ty + j]);
        }
        if (blockIdx.x == 0 && ty == 0) l1[nb + tx] = 0.0f;
    } else {
        for (int j = 0; j < 32; j += 8) {
            int h = hb + ty + j;
            int o = nb + tx;
            tile[ty + j][tx] = (o < N_IN) ? qw[(size_t)h * N_IN + o] : 0.0f;
        }
        __syncthreads();
        __hip_bfloat16* qt = (__hip_bfloat16*)qtb;
        for (int j = 0; j < 32; j += 8) {
            int o = nb + ty + j;
            int h = hb + tx;
            float v = tile[tx][ty + j];
            qt[(size_t)o * H_DIM + h] = __float2bfloat16(v * 0.0625f);
            q8[(size_t)o * H_DIM + h] = to_fp8(v);
        }
    }
}

// ---- GEMM_L1 (fp8): l1[i] = sum_o |sum_h q8[o][h]*k8[i][h]| (unscaled by 16^2;
//      folded out downstream). M=N=5120, K=256, tile 128x128, BK=128 (2 rounds),
//      LDS 2x16KB, XOR-swizzled 16B slots (key = row&7). ----
__launch_bounds__(256)
__global__ void gemm_l1(const unsigned char* __restrict__ q8,
                        const unsigned char* __restrict__ k8,
                        float* __restrict__ l1) {
    __shared__ unsigned char As8[128 * 128];   // 16 KB
    __shared__ unsigned char Bs8[128 * 128];   // 16 KB
    const int bm = blockIdx.x, bn = blockIdx.y;
    const int tid = threadIdx.x, lane = tid & 63, wid = tid >> 6;
    const int wave_m = wid >> 1, wave_n = wid & 1;
    const int r = lane >> 3;          // 0..7 row within chunk
    const int s = lane & 7;           // 0..7 16B slot
    const int quad = lane >> 4, cit = lane & 15;
    const int xk = cit & 7;           // fragment xor key (= row & 7)

    f32x4 acc[4][4];
    const f32x4 zf = {0.f, 0.f, 0.f, 0.f};
    for (int a = 0; a < 4; ++a)
        for (int b = 0; b < 4; ++b) acc[a][b] = zf;

    for (int kb = 0; kb < H_DIM; kb += 128) {
        __syncthreads();
        const int koff = kb + ((s ^ r) << 4);   // swizzled global k-group
        for (int c = 0; c < 4; ++c) {
            int q = wid * 4 + c;                // 1KB chunk 0..15 (8 rows each)
            int row = q * 8 + r;
            async_copy16(q8 + (size_t)(bm * 128 + row) * H_DIM + koff, As8 + q * 1024);
            async_copy16(k8 + (size_t)(bn * 128 + row) * H_DIM + koff, Bs8 + q * 1024);
        }
        __syncthreads();
        for (int ki = 0; ki < 4; ++ki) {        // 4 x K=32 per round
            int g = ki * 2 + (quad >> 1);       // global 16B group within row
            int lo8 = (quad & 1) << 3;
            int slot = ((g ^ xk) << 4) + lo8;
            long af[4], bf[4];
            for (int t = 0; t < 4; ++t) {
                int am = wave_m * 64 + t * 16 + cit;
                af[t] = *(const long*)(As8 + am * 128 + slot);
                int bn_ = wave_n * 64 + t * 16 + cit;
                bf[t] = *(const long*)(Bs8 + bn_ * 128 + slot);
            }
            for (int tm = 0; tm < 4; ++tm)
                for (int tn = 0; tn < 4; ++tn)
                    acc[tm][tn] = __builtin_amdgcn_mfma_f32_16x16x32_fp8_fp8(
                        af[tm], bf[tn], acc[tm][tn], 0, 0, 0);
        }
    }

    for (int tn = 0; tn < 4; ++tn) {
        int ig = bn * 128 + wave_n * 64 + tn * 16 + cit;   // column i
        float p = 0.0f;
        for (int tm = 0; tm < 4; ++tm) {
            f32x4 c = acc[tm][tn];
            p += fabsf(c.x) + fabsf(c.y) + fabsf(c.z) + fabsf(c.w);
        }
        p += __shfl_xor(p, 16);
        p += __shfl_xor(p, 32);
        if (quad == 0) atomicAdd(&l1[ig], p);
    }
}

// ---- GEMM3_F (build_vmat fused): part2[z][bd][h] =
//      sum_{i in 64-chunk} vmat[bd][i] * keyT[h][i],
//      vmat[b*3+e][i] = (1/max(l1[i]/16,eps)) * sum_d x[b,i,d]*vw[e,d]
//      computed directly into padded LDS (pitch 72 -> +4-bank row shift).
//      Grid (4 h-tiles, 80 z). Waves 2x2: wave tile 96x32. ----
#define AP 72    // As pitch in bf16: 144 B = 9*16 (aligned), 36 dw = +4 banks/row
__launch_bounds__(256)
__global__ void gemm3_f(const float* __restrict__ x, const float* __restrict__ vw,
                        const float* __restrict__ l1, const short* __restrict__ keyT,
                        float* __restrict__ part2) {
    __shared__ short As[NBD * AP];    // 27,648 B
    __shared__ short Bs[64 * 64];     // 8,192 B (XOR-swizzled 16B slots)
    const int bh = blockIdx.x;        // h tile (4)
    const int z  = blockIdx.y;        // i chunk (80)
    const int tid = threadIdx.x, lane = tid & 63, wid = tid >> 6;
    const int wave_m = wid >> 1, wave_n = wid & 1;
    const int rr = lane >> 3, ss = lane & 7;
    const int quad = lane >> 4, cit = lane & 15;

    // ---- build vmat tile into As ----
    {
        const int i_loc = tid & 63;
        const int grp   = tid >> 6;            // 4 groups x 16 b
        const int i = z * 64 + i_loc;
        const bool ok = (i < N_IN);
        float rcp = 0.0f;
        if (ok) rcp = 1.0f / fmaxf(l1[i] * 0.0625f, 1e-12f);
        float w00 = vw[0], w01 = vw[1], w02 = vw[2];
        float w10 = vw[3], w11 = vw[4], w12 = vw[5];
        float w20 = vw[6], w21 = vw[7], w22 = vw[8];
        __hip_bfloat16* as = (__hip_bfloat16*)As;
        for (int bo = 0; bo < 16; ++bo) {
            int b = grp * 16 + bo;
            float x0 = 0.f, x1 = 0.f, x2 = 0.f;
            if (ok) {
                const float* xp = x + ((size_t)b * N_IN + i) * 3;
                x0 = xp[0]; x1 = xp[1]; x2 = xp[2];
            }
            as[(b * 3 + 0) * AP + i_loc] = __float2bfloat16((x0 * w00 + x1 * w01 + x2 * w02) * rcp);
            as[(b * 3 + 1) * AP + i_loc] = __float2bfloat16((x0 * w10 + x1 * w11 + x2 * w12) * rcp);
            as[(b * 3 + 2) * AP + i_loc] = __float2bfloat16((x0 * w20 + x1 * w21 + x2 * w22) * rcp);
        }
    }
    // ---- stage Bs (keyT rows, swizzled) ----
    for (int c = 0; c < 2; ++c) {
        int q = wid * 2 + c;                   // 0..7 (1KB chunks)
        int row = q * 8 + rr;                  // h local 0..63
        int koff = z * 64 + ((ss ^ (rr & 7)) << 3);
        async_copy16(keyT + (size_t)(bh * 64 + row) * NPAD + koff, Bs + q * 512);
    }
    __syncthreads();

    f32x4 acc[6][2];
    const f32x4 zf = {0.f, 0.f, 0.f, 0.f};
    for (int a = 0; a < 6; ++a)
        for (int b = 0; b < 2; ++b) acc[a][b] = zf;

    for (int kk = 0; kk < 64; kk += 32) {
        bf16x8 af[6], bf[2];
        int g = (kk >> 3) + quad;
        for (int t = 0; t < 6; ++t) {
            int row = wave_m * 96 + t * 16 + cit;
            af[t] = *(const bf16x8*)(As + row * AP + kk + quad * 8);
        }
        for (int t = 0; t < 2; ++t) {
            int row = wave_n * 32 + t * 16 + cit;
            bf[t] = *(const bf16x8*)(Bs + row * 64 + ((g ^ (cit & 7)) << 3));
        }
        for (int tm = 0; tm < 6; ++tm)
            for (int tn = 0; tn < 2; ++tn)
                acc[tm][tn] = __builtin_amdgcn_mfma_f32_16x16x32_bf16(
                    af[tm], bf[tn], acc[tm][tn], 0, 0, 0);
    }

    float* pz = part2 + (size_t)z * (NBD * H_DIM);
    for (int tn = 0; tn < 2; ++tn) {
        int h = bh * 64 + wave_n * 32 + tn * 16 + cit;
        for (int tm = 0; tm < 6; ++tm) {
            int bd0 = wave_m * 96 + tm * 16 + quad * 4;
            f32x4 c = acc[tm][tn];
            for (int r2 = 0; r2 < 4; ++r2)
                pz[(size_t)(bd0 + r2) * H_DIM + h] = c[r2];
        }
    }
}

// ---- reduce_T: T[bd][h] = bf16(sum_z part2[z][bd][h]) ----
__global__ void reduce_T(const float* __restrict__ part2, short* __restrict__ T) {
    int idx = blockIdx.x * 256 + threadIdx.x;     // < 49152
    float s = 0.0f;
    for (int z = 0; z < SPLITZ; ++z)
        s += part2[(size_t)z * (NBD * H_DIM) + idx];
    ((__hip_bfloat16*)T)[idx] = __float2bfloat16(s);
}

// ---- GEMM4: y[o][bd] = sum_h qt[o][h] * T[bd][h]; out via LDS transpose.
//      M-tile 32 -> 160 blocks. Waves 2x2: wave tile 16x96. XOR-swizzled LDS. ----
#define CS_PITCH 196
__launch_bounds__(256)
__global__ void gemm4(const short* __restrict__ qt, const short* __restrict__ T,
                      float* __restrict__ out) {
    __shared__ __align__(16) char smem[28672];   // staging 28KB / CS 25KB union
    short* As = (short*)smem;                    // 32 x 64 (4 KB, swizzled)
    short* Bs = (short*)(smem + 4096);           // 192 x 64 (24 KB, swizzled)
    const int bm = blockIdx.x;                   // 160
    const int tid = threadIdx.x, lane = tid & 63, wid = tid >> 6;
    const int wave_m = wid >> 1, wave_n = wid & 1;
    const int rr = lane >> 3, ss = lane & 7;
    const int quad = lane >> 4, cit = lane & 15;

    f32x4 acc[6];
    const f32x4 zf = {0.f, 0.f, 0.f, 0.f};
    for (int b = 0; b < 6; ++b) acc[b] = zf;

    for (int kb = 0; kb < H_DIM; kb += 64) {
        __syncthreads();
        const int koff = kb + ((ss ^ (rr & 7)) << 3);
        {   // As: 4 chunks, one per wave
            int row = wid * 8 + rr;              // 0..31
            async_copy16(qt + (size_t)(bm * 32 + row) * H_DIM + koff, As + wid * 512);
        }
        for (int c = 0; c < 6; ++c) {            // Bs: 24 chunks
            int q = wid * 6 + c;
            int row = q * 8 + rr;                // 0..191
            async_copy16(T + (size_t)row * H_DIM + koff, Bs + q * 512);
        }
        __syncthreads();
        for (int kk = 0; kk < 64; kk += 32) {
            bf16x8 af, bf[6];
            int g = (kk >> 3) + quad;
            int slot = (g ^ (cit & 7)) << 3;
            {
                int row = wave_m * 16 + cit;
                af = *(const bf16x8*)(As + row * 64 + slot);
            }
            for (int t = 0; t < 6; ++t) {
                int row = wave_n * 96 + t * 16 + cit;
                bf[t] = *(const bf16x8*)(Bs + row * 64 + slot);
            }
            for (int tn = 0; tn < 6; ++tn)
                acc[tn] = __builtin_amdgcn_mfma_f32_16x16x32_bf16(
                    af, bf[tn], acc[tn], 0, 0, 0);
        }
    }

    __syncthreads();
    float* cs = (float*)smem;             // [32][CS_PITCH]
    for (int tn = 0; tn < 6; ++tn) {
        int bd = wave_n * 96 + tn * 16 + cit;
        int o0 = wave_m * 16 + quad * 4;
        f32x4 c = acc[tn];
        for (int r2 = 0; r2 < 4; ++r2)
            cs[(o0 + r2) * CS_PITCH + bd] = c[r2];
    }
    __syncthreads();
    // out[b][o][d]: 64 b x (32 o x 3 d) = 6144 floats; 96-float runs per b.
    for (int it = 0; it < 24; ++it) {
        int flat = it * 256 + tid;        // 0..6143
        int b = flat / 96;
        int w = flat - b * 96;
        int o_l = w / 3, d = w - o_l * 3;
        int og = bm * 32 + o_l;
        if (og < N_IN)
            out[(size_t)b * (N_IN * 3) + (size_t)og * 3 + d] =
                cs[o_l * CS_PITCH + b * 3 + d];
    }
}

extern "C" void kernel_launch(void* const* d_in, const int* in_sizes, int n_in,
                              void* d_out, int out_size, void* d_ws, size_t ws_size,
                              hipStream_t stream) {
    const float* x  = (const float*)d_in[0];
    const float* kw = (const float*)d_in[1];
    const float* qw = (const float*)d_in[2];
    const float* vw = (const float*)d_in[3];
    float* out = (float*)d_out;

    char* w = (char*)d_ws;
    short* qtb  = (short*)(w + 0);                        // 5120*256*2 = 2,621,440
    short* keyT = (short*)(w + 2621440);                  // 256*5120*2 = 2,621,440
    unsigned char* q8 = (unsigned char*)(w + 5242880);    // 5120*256   = 1,310,720
    unsigned char* k8 = (unsigned char*)(w + 6553600);    // 5120*256   = 1,310,720
    float* l1    = (float*)(w + 7864320);                 // 5120*4     = 20,480
    float* part2 = (float*)(w + 7884800);                 // 80*192*256*4 = 15,728,640
    short* T     = (short*)(w + 23613440);                // 192*256*2  = 98,304
    // total: 23,711,744 bytes

    conv_all<<<dim3(H_DIM / 32, NPAD / 32, 2), dim3(32, 8), 0, stream>>>(
        kw, qw, k8, keyT, q8, qtb, l1);
    gemm_l1<<<dim3(NPAD / 128, NPAD / 128), 256, 0, stream>>>(q8, k8, l1);
    gemm3_f<<<dim3(H_DIM / 64, SPLITZ), 256, 0, stream>>>(x, vw, l1, keyT, part2);
    reduce_T<<<(NBD * H_DIM) / 256, 256, 0, stream>>>(part2, T);
    gemm4<<<NPAD / 32, 256, 0, stream>>>(qtb, T, out);
}